// Round 1
// baseline (389.920 us; speedup 1.0000x reference)
//
#include <hip/hip_runtime.h>

#define N_CTX  256
#define T_LEN  1024
#define N_SEQ  4096
#define HID    16

// ---- fast scalar math on raw gfx950 ops ----
__device__ __forceinline__ float fexp2(float x) { return __builtin_amdgcn_exp2f(x); }
__device__ __forceinline__ float frcp (float x) { return __builtin_amdgcn_rcpf(x); }

// sigmoid(x) = 1/(1+2^(-x*log2e)); x->-inf: e->inf, rcp(inf)=0 OK; no NaN path
__device__ __forceinline__ float sigm(float x) {
    float e = fexp2(-1.4426950408889634f * x);
    return frcp(1.0f + e);
}
// tanh(x) = (a-1)/(a+1), a = 2^(2x*log2e), clamp exponent so a stays finite
__device__ __forceinline__ float tanh_fast(float x) {
    float a = fexp2(fminf(2.8853901631790583f * x, 126.0f));
    return (a - 1.0f) * frcp(a + 1.0f);
}

// ---- 16-lane butterfly reduction via DPP (pure VALU, result in all 16 lanes) ----
template <int CTRL>
__device__ __forceinline__ float dpp_add(float x) {
    int y = __builtin_amdgcn_mov_dpp(__float_as_int(x), CTRL, 0xf, 0xf, true);
    return x + __int_as_float(y);
}
__device__ __forceinline__ float red16(float x) {
    x = dpp_add<0xB1>(x);   // quad_perm [1,0,3,2]  : xor 1
    x = dpp_add<0x4E>(x);   // quad_perm [2,3,0,1]  : xor 2
    x = dpp_add<0x124>(x);  // row_ror:4            : +other quad pair
    x = dpp_add<0x128>(x);  // row_ror:8            : full 16-lane sum
    return x;
}

// One lane per hidden unit; 16 lanes per sequence; DPP rows align with groups.
__global__ __launch_bounds__(256) void openlstm_kernel(
    const float* __restrict__ u,     // (B, T, 4) = [x0 x1 y0 y1]
    const float* __restrict__ w_ih,  // (64, 2)
    const float* __restrict__ w_hh,  // (64, 2)
    const float* __restrict__ b_ih,  // (64)
    const float* __restrict__ b_hh,  // (64)
    const float* __restrict__ w_hr,  // (2, 16)
    float* __restrict__ out)         // (B, T, 2)
{
    const int tid = blockIdx.x * blockDim.x + threadIdx.x;
    const int seq = tid >> 4;
    const int j   = tid & 15;

    // per-lane weights: gate rows {j, 16+j, 32+j, 48+j} = i, f, g, o
    float wi0[4], wi1[4], wh0[4], wh1[4], bs[4];
#pragma unroll
    for (int q = 0; q < 4; ++q) {
        const int row = q * 16 + j;
        wi0[q] = w_ih[row * 2 + 0];
        wi1[q] = w_ih[row * 2 + 1];
        wh0[q] = w_hh[row * 2 + 0];
        wh1[q] = w_hh[row * 2 + 1];
        bs[q]  = b_ih[row] + b_hh[row];
    }
    const float whr0 = w_hr[j];
    const float whr1 = w_hr[16 + j];

    const float4* __restrict__ up = (const float4*)u + (size_t)seq * T_LEN;
    float2* __restrict__ op = (float2*)out + (size_t)seq * T_LEN;

    float c = 0.0f, rh0 = 0.0f, rh1 = 0.0f;
    float4 x = up[0];

    // ---- estimation phase: h is teacher-forced (y_t); only c carries ----
    for (int t = 0; t < N_CTX; ++t) {
        float4 xn = up[t + 1];               // prefetch (independent of chain)
        const float h0 = x.z, h1 = x.w;
        float g[4];
#pragma unroll
        for (int q = 0; q < 4; ++q)
            g[q] = fmaf(h1, wh1[q], fmaf(h0, wh0[q],
                   fmaf(x.y, wi1[q], fmaf(x.x, wi0[q], bs[q]))));
        const float si = sigm(g[0]);
        const float sf = sigm(g[1]);
        const float tg = tanh_fast(g[2]);
        const float so = sigm(g[3]);
        c = fmaf(sf, c, si * tg);
        const float s = so * tanh_fast(c);
        rh0 = red16(s * whr0);
        rh1 = red16(s * whr1);
        if (j == 0) op[t] = make_float2(rh0, rh1);
        x = xn;
    }

    // ---- prediction phase: h recurrent through the DPP reduction ----
    for (int t = N_CTX; t < T_LEN; ++t) {
        float4 xn = up[t + 1 < T_LEN ? t + 1 : t];
        const float h0 = rh0, h1 = rh1;
        float g[4];
#pragma unroll
        for (int q = 0; q < 4; ++q)
            g[q] = fmaf(h1, wh1[q], fmaf(h0, wh0[q],
                   fmaf(x.y, wi1[q], fmaf(x.x, wi0[q], bs[q]))));
        const float si = sigm(g[0]);
        const float sf = sigm(g[1]);
        const float tg = tanh_fast(g[2]);
        const float so = sigm(g[3]);
        c = fmaf(sf, c, si * tg);
        const float s = so * tanh_fast(c);
        rh0 = red16(s * whr0);
        rh1 = red16(s * whr1);
        if (j == 0) op[t] = make_float2(rh0, rh1);
        x = xn;
    }
}

extern "C" void kernel_launch(void* const* d_in, const int* in_sizes, int n_in,
                              void* d_out, int out_size, void* d_ws, size_t ws_size,
                              hipStream_t stream) {
    const float* u    = (const float*)d_in[0];
    const float* w_ih = (const float*)d_in[1];
    const float* w_hh = (const float*)d_in[2];
    const float* b_ih = (const float*)d_in[3];
    const float* b_hh = (const float*)d_in[4];
    const float* w_hr = (const float*)d_in[5];
    float* out = (float*)d_out;

    const int threads = 256;                          // 16 sequences / block
    const int blocks  = (N_SEQ * HID) / threads;      // 256 blocks -> 1 per CU
    hipLaunchKernelGGL(openlstm_kernel, dim3(blocks), dim3(threads), 0, stream,
                       u, w_ih, w_hh, b_ih, b_hh, w_hr, out);
}

// Round 2
// 256.437 us; speedup vs baseline: 1.5205x; 1.5205x over previous
//
#include <hip/hip_runtime.h>

#define N_CTX  256
#define T_LEN  1024
#define N_SEQ  4096
#define CHUNK  16

// ---- fast scalar math on raw gfx950 trans ops ----
__device__ __forceinline__ float fexp2(float x){ return __builtin_amdgcn_exp2f(x); }
__device__ __forceinline__ float frcp (float x){ return __builtin_amdgcn_rcpf(x); }

// sigmoid(x) = 1/(1+2^(-x*log2e)); x->-inf: exp2->inf, rcp(inf)=0, no NaN
__device__ __forceinline__ float sigm(float x){
    return frcp(1.0f + fexp2(-1.4426950408889634f * x));
}
// tanh(x) = (a-1)/(a+1), a = 2^(2x*log2e), clamped so a stays finite
__device__ __forceinline__ float tanh_fast(float x){
    float a = fexp2(fminf(2.8853901631790583f * x, 126.0f));
    return (a - 1.0f) * frcp(a + 1.0f);
}

// ---- 16-lane butterfly reduction via DPP (pure VALU, broadcast result) ----
template<int CTRL>
__device__ __forceinline__ float dpp_add(float x){
    int y = __builtin_amdgcn_mov_dpp(__float_as_int(x), CTRL, 0xf, 0xf, true);
    return x + __int_as_float(y);
}
__device__ __forceinline__ float red16(float x){
    x = dpp_add<0xB1>(x);   // quad_perm xor1
    x = dpp_add<0x4E>(x);   // quad_perm xor2
    x = dpp_add<0x124>(x);  // row_ror:4
    x = dpp_add<0x128>(x);  // row_ror:8 -> full 16-lane sum in all lanes
    return x;
}

struct LaneW {
    float wi0[4], wi1[4], wh0[4], wh1[4], bs[4];
    float whr0, whr1;
};

template<bool TEACHER>
__device__ __forceinline__ void lstm_step(const float4 x, const LaneW& L,
                                          float& c, float& rh0, float& rh1)
{
    const float h0 = TEACHER ? x.z : rh0;
    const float h1 = TEACHER ? x.w : rh1;
    float g[4];
#pragma unroll
    for (int q = 0; q < 4; ++q)
        g[q] = fmaf(h1, L.wh1[q], fmaf(h0, L.wh0[q],
               fmaf(x.y, L.wi1[q], fmaf(x.x, L.wi0[q], L.bs[q]))));
    const float si = sigm(g[0]);
    const float sf = sigm(g[1]);
    const float tg = tanh_fast(g[2]);
    const float so = sigm(g[3]);
    c = fmaf(sf, c, si * tg);
    const float s = so * tanh_fast(c);
    rh0 = red16(s * L.whr0);
    rh1 = red16(s * L.whr1);
}

__device__ __forceinline__ void load_chunk(float4* b, const float4* __restrict__ up, int base){
#pragma unroll
    for (int i = 0; i < CHUNK; ++i) b[i] = up[base + i];   // 16 independent dwordx4
}

template<bool TEACHER>
__device__ __forceinline__ void compute_chunk(const float4* b, int base, const LaneW& L,
                                              float& c, float& rh0, float& rh1,
                                              float2* __restrict__ op, int j)
{
#pragma unroll
    for (int i = 0; i < CHUNK; ++i) {
        lstm_step<TEACHER>(b[i], L, c, rh0, rh1);
        if (j == 0) op[base + i] = make_float2(rh0, rh1);
    }
}

// 16 lanes per sequence (one per hidden unit); 4 sequences per wave.
__global__ __launch_bounds__(256) void openlstm_kernel(
    const float* __restrict__ u,     // (B, T, 4) = [x0 x1 y0 y1]
    const float* __restrict__ w_ih,  // (64, 2)
    const float* __restrict__ w_hh,  // (64, 2)
    const float* __restrict__ b_ih,  // (64)
    const float* __restrict__ b_hh,  // (64)
    const float* __restrict__ w_hr,  // (2, 16)
    float* __restrict__ out)         // (B, T, 2)
{
    const int tid = blockIdx.x * blockDim.x + threadIdx.x;
    const int seq = tid >> 4;
    const int j   = tid & 15;

    LaneW L;
#pragma unroll
    for (int q = 0; q < 4; ++q) {
        const int row = q * 16 + j;   // gate rows {j,16+j,32+j,48+j} = i,f,g,o
        L.wi0[q] = w_ih[row*2+0];
        L.wi1[q] = w_ih[row*2+1];
        L.wh0[q] = w_hh[row*2+0];
        L.wh1[q] = w_hh[row*2+1];
        L.bs[q]  = b_ih[row] + b_hh[row];
    }
    L.whr0 = w_hr[j];
    L.whr1 = w_hr[16+j];

    const float4* __restrict__ up = (const float4*)u + (size_t)seq * T_LEN;
    float2* __restrict__ op = (float2*)out + (size_t)seq * T_LEN;

    float c = 0.0f, rh0 = 0.0f, rh1 = 0.0f;
    float4 bufA[CHUNK], bufB[CHUNK];   // static ping-pong: never runtime-indexed

    load_chunk(bufA, up, 0);

    // ---- estimation: h teacher-forced; chunks [0,256) ----
#pragma unroll 1
    for (int base = 0; base < N_CTX; base += 2*CHUNK) {
        load_chunk(bufB, up, base + CHUNK);
        compute_chunk<true>(bufA, base, L, c, rh0, rh1, op, j);
        load_chunk(bufA, up, base + 2*CHUNK);   // last est iter preloads chunk @256 for pred
        compute_chunk<true>(bufB, base + CHUNK, L, c, rh0, rh1, op, j);
    }

    // ---- prediction: h recurrent; chunks [256,1024) ----
#pragma unroll 1
    for (int base = N_CTX; base < T_LEN; base += 2*CHUNK) {
        load_chunk(bufB, up, base + CHUNK);
        compute_chunk<false>(bufA, base, L, c, rh0, rh1, op, j);
        if (base + 2*CHUNK < T_LEN)
            load_chunk(bufA, up, base + 2*CHUNK);
        compute_chunk<false>(bufB, base + CHUNK, L, c, rh0, rh1, op, j);
    }
}

extern "C" void kernel_launch(void* const* d_in, const int* in_sizes, int n_in,
                              void* d_out, int out_size, void* d_ws, size_t ws_size,
                              hipStream_t stream) {
    const float* u    = (const float*)d_in[0];
    const float* w_ih = (const float*)d_in[1];
    const float* w_hh = (const float*)d_in[2];
    const float* b_ih = (const float*)d_in[3];
    const float* b_hh = (const float*)d_in[4];
    const float* w_hr = (const float*)d_in[5];
    float* out = (float*)d_out;

    const int threads = 256;                       // 16 sequences / block
    const int blocks  = (N_SEQ * 16) / threads;    // 256 blocks -> 1 per CU
    hipLaunchKernelGGL(openlstm_kernel, dim3(blocks), dim3(threads), 0, stream,
                       u, w_ih, w_hh, b_ih, b_hh, w_hr, out);
}

// Round 3
// 251.711 us; speedup vs baseline: 1.5491x; 1.0188x over previous
//
#include <hip/hip_runtime.h>

#define N_CTX  256
#define T_LEN  1024
#define N_SEQ  4096
#define CHUNK  16
#define NCHUNK (T_LEN / CHUNK)          // 32
#define CTXCK  (N_CTX / CHUNK)          // 16 teacher-forced chunks

typedef float v2f __attribute__((ext_vector_type(2)));

__device__ __forceinline__ float fexp2(float x){ return __builtin_amdgcn_exp2f(x); }
__device__ __forceinline__ float frcp (float x){ return __builtin_amdgcn_rcpf(x); }
__device__ __forceinline__ v2f pk_fma(v2f a, v2f b, v2f c){ return __builtin_elementwise_fma(a, b, c); }

#define L1C 1.4426950408889634f   /* log2(e)  */
#define L2C 2.8853901631790583f   /* 2 log2(e)*/
#define ECLAMP 60.0f              /* exp2 arg clamp: keeps (1+u)(v+1) finite */

// ---- 16-lane butterfly reduction via DPP (VALU pipe, broadcasts result) ----
template<int CTRL>
__device__ __forceinline__ float dpp_add(float x){
    int y = __builtin_amdgcn_mov_dpp(__float_as_int(x), CTRL, 0xf, 0xf, true);
    return x + __int_as_float(y);
}
__device__ __forceinline__ float red16(float x){
    x = dpp_add<0xB1>(x);   // quad_perm xor1
    x = dpp_add<0x4E>(x);   // quad_perm xor2
    x = dpp_add<0x124>(x);  // row_ror:4
    x = dpp_add<0x128>(x);  // row_ror:8 -> full 16-lane sum in all lanes
    return x;
}

struct LaneW {
    v2f wi0_if, wi1_if, wi0_go, wi1_go;   // input weights, gate pairs (i,f) and (g,o)
    v2f wh0_if, wh1_if, wh0_go, wh1_go;   // hidden weights
    v2f bs_if, bs_go;                     // summed bias
    float whr0, whr1;                     // projection row for this lane's unit
};

struct ChunkX {
    v2f   xif[CHUNK];   // bias + x-part of gates (i,f)
    v2f   xgo[CHUNK];   // bias + x-part of gates (g,o)
    float y0[CHUNK];    // teacher h0
    float y1[CHUNK];    // teacher h1
};

__device__ __forceinline__ void load_chunk(float4* b, const float4* __restrict__ up, int base){
#pragma unroll
    for (int i = 0; i < CHUNK; ++i) b[i] = up[base + i];   // 16 independent dwordx4
}

__device__ __forceinline__ void transform_chunk(ChunkX& X, const float4* raw, const LaneW& L){
#pragma unroll
    for (int i = 0; i < CHUNK; ++i) {
        const float4 x = raw[i];
        v2f xx = {x.x, x.x}, xy = {x.y, x.y};
        X.xif[i] = pk_fma(xy, L.wi1_if, pk_fma(xx, L.wi0_if, L.bs_if));
        X.xgo[i] = pk_fma(xy, L.wi1_go, pk_fma(xx, L.wi0_go, L.bs_go));
        X.y0[i]  = x.z;
        X.y1[i]  = x.w;
    }
}

template<bool TEACHER>
__device__ __forceinline__ void lstm_step(v2f xif, v2f xgo, float y0, float y1,
                                          const LaneW& L, float& c, float& rh0, float& rh1)
{
    const float h0 = TEACHER ? y0 : rh0;
    const float h1 = TEACHER ? y1 : rh1;
    v2f hh0 = {h0, h0}, hh1 = {h1, h1};
    v2f gif = pk_fma(hh1, L.wh1_if, pk_fma(hh0, L.wh0_if, xif));
    v2f ggo = pk_fma(hh1, L.wh1_go, pk_fma(hh0, L.wh0_go, xgo));
    // u=e^-i, ef=e^-f, v=e^2g, eo=e^-o  (clamped exponents -> denominators finite)
    const float u  = fexp2(fminf(gif.x * -L1C, ECLAMP));
    const float ef = fexp2(fminf(gif.y * -L1C, ECLAMP));
    const float v  = fexp2(fminf(ggo.x *  L2C, ECLAMP));
    const float eo = fexp2(fminf(ggo.y * -L1C, ECLAMP));
    const float sf   = frcp(1.0f + ef);                               // sigmoid(f)
    const float sitg = (v - 1.0f) * frcp((1.0f + u) * (v + 1.0f));    // sigm(i)*tanh(g)
    c = fmaf(sf, c, sitg);
    const float w = fexp2(fminf(c * L2C, ECLAMP));
    const float s = (w - 1.0f) * frcp((1.0f + eo) * (w + 1.0f));      // sigm(o)*tanh(c)
    rh0 = red16(s * L.whr0);
    rh1 = red16(s * L.whr1);
}

template<bool TEACHER>
__device__ __forceinline__ void chain_chunk(const ChunkX& X, int baseT, const LaneW& L,
                                            float& c, float& rh0, float& rh1,
                                            float4* __restrict__ opv, bool store_lane)
{
    float o[8];
#pragma unroll
    for (int i = 0; i < CHUNK; ++i) {
        lstm_step<TEACHER>(X.xif[i], X.xgo[i], X.y0[i], X.y1[i], L, c, rh0, rh1);
        o[(i & 3) * 2]     = rh0;
        o[(i & 3) * 2 + 1] = rh1;
        if ((i & 3) == 3 && store_lane) {          // batch: 4 steps -> 2x dwordx4
            const int f4i = (baseT + i - 3) >> 1;  // out is (T,2) floats -> t/2 float4s
            opv[f4i]     = make_float4(o[0], o[1], o[2], o[3]);
            opv[f4i + 1] = make_float4(o[4], o[5], o[6], o[7]);
        }
    }
}

// 16 lanes per sequence (one per hidden unit); 4 sequences per wave; 1 wave/SIMD.
__global__ __launch_bounds__(256, 1) void openlstm_kernel(
    const float* __restrict__ u,     // (B, T, 4) = [x0 x1 y0 y1]
    const float* __restrict__ w_ih,  // (64, 2)
    const float* __restrict__ w_hh,  // (64, 2)
    const float* __restrict__ b_ih,  // (64)
    const float* __restrict__ b_hh,  // (64)
    const float* __restrict__ w_hr,  // (2, 16)
    float* __restrict__ out)         // (B, T, 2)
{
    const int tid = blockIdx.x * blockDim.x + threadIdx.x;
    const int seq = tid >> 4;
    const int j   = tid & 15;

    LaneW L;
    {   // gate rows {j, 16+j, 32+j, 48+j} = i, f, g, o
        const int ri = j, rf = 16 + j, rg = 32 + j, ro = 48 + j;
        L.wi0_if = (v2f){w_ih[ri*2+0], w_ih[rf*2+0]};
        L.wi1_if = (v2f){w_ih[ri*2+1], w_ih[rf*2+1]};
        L.wi0_go = (v2f){w_ih[rg*2+0], w_ih[ro*2+0]};
        L.wi1_go = (v2f){w_ih[rg*2+1], w_ih[ro*2+1]};
        L.wh0_if = (v2f){w_hh[ri*2+0], w_hh[rf*2+0]};
        L.wh1_if = (v2f){w_hh[ri*2+1], w_hh[rf*2+1]};
        L.wh0_go = (v2f){w_hh[rg*2+0], w_hh[ro*2+0]};
        L.wh1_go = (v2f){w_hh[rg*2+1], w_hh[ro*2+1]};
        L.bs_if  = (v2f){b_ih[ri] + b_hh[ri], b_ih[rf] + b_hh[rf]};
        L.bs_go  = (v2f){b_ih[rg] + b_hh[rg], b_ih[ro] + b_hh[ro]};
        L.whr0   = w_hr[j];
        L.whr1   = w_hr[16 + j];
    }

    const float4* __restrict__ up = (const float4*)u + (size_t)seq * T_LEN;
    float4* __restrict__ opv = (float4*)((float2*)out + (size_t)seq * T_LEN);
    const bool sl = (j == 0);

    float c = 0.0f, rh0 = 0.0f, rh1 = 0.0f;
    float4 rawA[CHUNK], rawB[CHUNK];   // static ping-pong, never runtime-indexed

    load_chunk(rawA, up, 0);
    load_chunk(rawB, up, CHUNK);

#pragma unroll 1
    for (int ck = 0; ck < NCHUNK; ck += 2) {
        {
            ChunkX XA;
            transform_chunk(XA, rawA, L);
            if (ck + 2 < NCHUNK) load_chunk(rawA, up, (ck + 2) * CHUNK);
            if (ck < CTXCK) chain_chunk<true >(XA, ck * CHUNK, L, c, rh0, rh1, opv, sl);
            else            chain_chunk<false>(XA, ck * CHUNK, L, c, rh0, rh1, opv, sl);
        }
        {
            ChunkX XB;
            transform_chunk(XB, rawB, L);
            if (ck + 3 < NCHUNK) load_chunk(rawB, up, (ck + 3) * CHUNK);
            if (ck + 1 < CTXCK) chain_chunk<true >(XB, (ck + 1) * CHUNK, L, c, rh0, rh1, opv, sl);
            else                chain_chunk<false>(XB, (ck + 1) * CHUNK, L, c, rh0, rh1, opv, sl);
        }
    }
}

extern "C" void kernel_launch(void* const* d_in, const int* in_sizes, int n_in,
                              void* d_out, int out_size, void* d_ws, size_t ws_size,
                              hipStream_t stream) {
    const float* u    = (const float*)d_in[0];
    const float* w_ih = (const float*)d_in[1];
    const float* w_hh = (const float*)d_in[2];
    const float* b_ih = (const float*)d_in[3];
    const float* b_hh = (const float*)d_in[4];
    const float* w_hr = (const float*)d_in[5];
    float* out = (float*)d_out;

    const int threads = 256;                       // 16 sequences / block
    const int blocks  = (N_SEQ * 16) / threads;    // 256 blocks -> 1 per CU
    hipLaunchKernelGGL(openlstm_kernel, dim3(blocks), dim3(threads), 0, stream,
                       u, w_ih, w_hh, b_ih, b_hh, w_hr, out);
}

// Round 4
// 226.924 us; speedup vs baseline: 1.7183x; 1.1092x over previous
//
#include <hip/hip_runtime.h>

#define N_CTX  256
#define T_LEN  1024
#define N_SEQ  4096
#define CHUNK  16
#define NCHUNK (T_LEN / CHUNK)          // 32
#define CTXCK  (N_CTX / CHUNK)          // 16 teacher-forced chunks

typedef float v2f __attribute__((ext_vector_type(2)));

__device__ __forceinline__ float fexp2(float x){ return __builtin_amdgcn_exp2f(x); }
__device__ __forceinline__ float frcp (float x){ return __builtin_amdgcn_rcpf(x); }
__device__ __forceinline__ v2f pk_fma(v2f a, v2f b, v2f c){ return __builtin_elementwise_fma(a, b, c); }

#define L1C 1.4426950408889634f   /* log2(e)   */
#define L2C 2.8853901631790583f   /* 2 log2(e) */
#define WCLAMP 100.0f             /* only state-dependent exponent needs a clamp */

// ---- packed 16-lane butterfly via DPP: 2 mov_dpp + 1 pk_add per level ----
template<int CTRL>
__device__ __forceinline__ v2f dpp_add2(v2f x){
    int y0 = __builtin_amdgcn_mov_dpp(__float_as_int(x.x), CTRL, 0xf, 0xf, true);
    int y1 = __builtin_amdgcn_mov_dpp(__float_as_int(x.y), CTRL, 0xf, 0xf, true);
    v2f y = { __int_as_float(y0), __int_as_float(y1) };
    return x + y;                      // v_pk_add_f32
}
__device__ __forceinline__ v2f red16_2(v2f x){
    x = dpp_add2<0xB1>(x);    // quad_perm xor1
    x = dpp_add2<0x4E>(x);    // quad_perm xor2
    x = dpp_add2<0x124>(x);   // row_ror:4
    x = dpp_add2<0x128>(x);   // row_ror:8 -> full 16-lane sum, broadcast
    return x;
}

struct LaneW {                         // ALL gate weights prescaled: (i,f,o)*-L1C, g*+L2C
    v2f wi0_if, wi1_if, wi0_go, wi1_go;
    v2f wh0_if, wh1_if, wh0_go, wh1_go;
    v2f bs_if, bs_go;
    v2f whr;                           // (w_hr[0][j], w_hr[1][j]) unscaled
};

struct ChunkX {
    v2f   xif[CHUNK];                  // prescaled bias + x-part, gates (i,f)
    v2f   xgo[CHUNK];                  // prescaled bias + x-part, gates (g,o)
    float y0[CHUNK], y1[CHUNK];        // raw teacher h
};

__device__ __forceinline__ void load_chunk(float4* b, const float4* __restrict__ up, int base){
#pragma unroll
    for (int i = 0; i < CHUNK; ++i) b[i] = up[base + i];   // 16 independent dwordx4
}

__device__ __forceinline__ void transform_chunk(ChunkX& X, const float4* raw, const LaneW& L){
#pragma unroll
    for (int i = 0; i < CHUNK; ++i) {
        const float4 x = raw[i];
        v2f xx = {x.x, x.x}, xy = {x.y, x.y};
        X.xif[i] = pk_fma(xy, L.wi1_if, pk_fma(xx, L.wi0_if, L.bs_if));
        X.xgo[i] = pk_fma(xy, L.wi1_go, pk_fma(xx, L.wi0_go, L.bs_go));
        X.y0[i]  = x.z;
        X.y1[i]  = x.w;
    }
}

template<bool TEACHER>
__device__ __forceinline__ void lstm_step(v2f xif, v2f xgo, float y0, float y1,
                                          const LaneW& L, float& c, v2f& rh)
{
    const float h0 = TEACHER ? y0 : rh.x;
    const float h1 = TEACHER ? y1 : rh.y;
    v2f hh0 = {h0, h0}, hh1 = {h1, h1};
    v2f gif = pk_fma(hh1, L.wh1_if, pk_fma(hh0, L.wh0_if, xif));  // = (-L1C*i, -L1C*f)
    v2f ggo = pk_fma(hh1, L.wh1_go, pk_fma(hh0, L.wh0_go, xgo));  // = ( L2C*g, -L1C*o)
    const float u  = fexp2(gif.x);     // e^-i   (|arg|<~16, no clamp needed)
    const float ef = fexp2(gif.y);     // e^-f
    const float v  = fexp2(ggo.x);     // e^{2g}
    const float eo = fexp2(ggo.y);     // e^-o
    // c' = sigm(f)*c + sigm(i)*tanh(g) with ONE rcp:
    const float A   = (1.0f + u) * (v + 1.0f);
    const float B   = 1.0f + ef;
    const float t   = (v - 1.0f) * B;
    const float num = fmaf(c, A, t);
    c = num * frcp(A * B);
    const float w = fexp2(fminf(L2C * c, WCLAMP));                // e^{2c}, clamped
    const float s = (w - 1.0f) * frcp((1.0f + eo) * (w + 1.0f));  // sigm(o)*tanh(c)
    v2f ss = {s, s};
    rh = red16_2(ss * L.whr);          // packed projection + packed butterfly
}

template<bool TEACHER>
__device__ __forceinline__ void chain_chunk(const ChunkX& X, int baseT, const LaneW& L,
                                            float& c, v2f& rh,
                                            float4* __restrict__ opv, bool store_lane)
{
    float o[8];
#pragma unroll
    for (int i = 0; i < CHUNK; ++i) {
        lstm_step<TEACHER>(X.xif[i], X.xgo[i], X.y0[i], X.y1[i], L, c, rh);
        o[(i & 3) * 2]     = rh.x;
        o[(i & 3) * 2 + 1] = rh.y;
        if ((i & 3) == 3 && store_lane) {          // 4 steps -> 2x dwordx4
            const int f4i = (baseT + i - 3) >> 1;
            opv[f4i]     = make_float4(o[0], o[1], o[2], o[3]);
            opv[f4i + 1] = make_float4(o[4], o[5], o[6], o[7]);
        }
    }
}

// 16 lanes per sequence (one per hidden unit); 4 sequences per wave; 1 wave/SIMD.
__global__ __launch_bounds__(256, 1) void openlstm_kernel(
    const float* __restrict__ u,     // (B, T, 4) = [x0 x1 y0 y1]
    const float* __restrict__ w_ih,  // (64, 2)
    const float* __restrict__ w_hh,  // (64, 2)
    const float* __restrict__ b_ih,  // (64)
    const float* __restrict__ b_hh,  // (64)
    const float* __restrict__ w_hr,  // (2, 16)
    float* __restrict__ out)         // (B, T, 2)
{
    const int tid = blockIdx.x * blockDim.x + threadIdx.x;
    const int seq = tid >> 4;
    const int j   = tid & 15;

    LaneW L;
    {   // gate rows {j, 16+j, 32+j, 48+j} = i, f, g, o ; prescale into exp2 domain
        const int ri = j, rf = 16 + j, rg = 32 + j, ro = 48 + j;
        const v2f sif = {-L1C, -L1C};          // (i, f)
        const v2f sgo = { L2C, -L1C};          // (g, o)
        L.wi0_if = sif * (v2f){w_ih[ri*2+0], w_ih[rf*2+0]};
        L.wi1_if = sif * (v2f){w_ih[ri*2+1], w_ih[rf*2+1]};
        L.wi0_go = sgo * (v2f){w_ih[rg*2+0], w_ih[ro*2+0]};
        L.wi1_go = sgo * (v2f){w_ih[rg*2+1], w_ih[ro*2+1]};
        L.wh0_if = sif * (v2f){w_hh[ri*2+0], w_hh[rf*2+0]};
        L.wh1_if = sif * (v2f){w_hh[ri*2+1], w_hh[rf*2+1]};
        L.wh0_go = sgo * (v2f){w_hh[rg*2+0], w_hh[ro*2+0]};
        L.wh1_go = sgo * (v2f){w_hh[rg*2+1], w_hh[ro*2+1]};
        L.bs_if  = sif * (v2f){b_ih[ri] + b_hh[ri], b_ih[rf] + b_hh[rf]};
        L.bs_go  = sgo * (v2f){b_ih[rg] + b_hh[rg], b_ih[ro] + b_hh[ro]};
        L.whr    = (v2f){w_hr[j], w_hr[16 + j]};
    }

    const float4* __restrict__ up = (const float4*)u + (size_t)seq * T_LEN;
    float4* __restrict__ opv = (float4*)((float2*)out + (size_t)seq * T_LEN);
    const bool sl = (j == 0);

    float c = 0.0f;
    v2f rh = {0.0f, 0.0f};
    float4 rawA[CHUNK], rawB[CHUNK];   // static ping-pong, never runtime-indexed

    load_chunk(rawA, up, 0);
    load_chunk(rawB, up, CHUNK);

#pragma unroll 1
    for (int ck = 0; ck < NCHUNK; ck += 2) {
        {
            ChunkX XA;
            transform_chunk(XA, rawA, L);
            if (ck + 2 < NCHUNK) load_chunk(rawA, up, (ck + 2) * CHUNK);
            if (ck < CTXCK) chain_chunk<true >(XA, ck * CHUNK, L, c, rh, opv, sl);
            else            chain_chunk<false>(XA, ck * CHUNK, L, c, rh, opv, sl);
        }
        {
            ChunkX XB;
            transform_chunk(XB, rawB, L);
            if (ck + 3 < NCHUNK) load_chunk(rawB, up, (ck + 3) * CHUNK);
            if (ck + 1 < CTXCK) chain_chunk<true >(XB, (ck + 1) * CHUNK, L, c, rh, opv, sl);
            else                chain_chunk<false>(XB, (ck + 1) * CHUNK, L, c, rh, opv, sl);
        }
    }
}

extern "C" void kernel_launch(void* const* d_in, const int* in_sizes, int n_in,
                              void* d_out, int out_size, void* d_ws, size_t ws_size,
                              hipStream_t stream) {
    const float* u    = (const float*)d_in[0];
    const float* w_ih = (const float*)d_in[1];
    const float* w_hh = (const float*)d_in[2];
    const float* b_ih = (const float*)d_in[3];
    const float* b_hh = (const float*)d_in[4];
    const float* w_hr = (const float*)d_in[5];
    float* out = (float*)d_out;

    const int threads = 256;                       // 16 sequences / block
    const int blocks  = (N_SEQ * 16) / threads;    // 256 blocks -> 1 per CU
    hipLaunchKernelGGL(openlstm_kernel, dim3(blocks), dim3(threads), 0, stream,
                       u, w_ih, w_hh, b_ih, b_hh, w_hr, out);
}

// Round 6
// 217.683 us; speedup vs baseline: 1.7912x; 1.0425x over previous
//
#include <hip/hip_runtime.h>

#define N_CTX  256
#define T_LEN  1024
#define N_SEQ  4096
#define CHUNK  16
#define NCHUNK (T_LEN / CHUNK)          // 32
#define CTXCK  (N_CTX / CHUNK)          // 16 teacher-forced chunks

typedef float v2f __attribute__((ext_vector_type(2)));

__device__ __forceinline__ float fexp2(float x){ return __builtin_amdgcn_exp2f(x); }
__device__ __forceinline__ float frcp (float x){ return __builtin_amdgcn_rcpf(x); }
__device__ __forceinline__ v2f pk_fma(v2f a, v2f b, v2f c){ return __builtin_elementwise_fma(a, b, c); }

#define L1C 1.4426950408889634f   /* log2(e)   */
#define L2C 2.8853901631790583f   /* 2 log2(e) */
#define WCLAMP 100.0f             /* only the state-dependent exponent needs a clamp */

// ---- packed 16-lane butterfly via DPP: 2 mov_dpp + 1 pk_add per level ----
template<int CTRL>
__device__ __forceinline__ v2f dpp_add2(v2f x){
    int y0 = __builtin_amdgcn_mov_dpp(__float_as_int(x.x), CTRL, 0xf, 0xf, true);
    int y1 = __builtin_amdgcn_mov_dpp(__float_as_int(x.y), CTRL, 0xf, 0xf, true);
    v2f y = { __int_as_float(y0), __int_as_float(y1) };
    return x + y;                      // v_pk_add_f32
}
__device__ __forceinline__ v2f red16_2(v2f x){
    x = dpp_add2<0xB1>(x);    // quad_perm xor1
    x = dpp_add2<0x4E>(x);    // quad_perm xor2
    x = dpp_add2<0x124>(x);   // row_ror:4
    x = dpp_add2<0x128>(x);   // row_ror:8 -> full 16-lane sum, broadcast
    return x;
}

struct LaneW {                         // gate weights prescaled: (i,f,o)*-L1C, g*+L2C
    v2f wi0_if, wi1_if, wi0_go, wi1_go;
    v2f wh0_if, wh1_if, wh0_go, wh1_go;
    v2f bs_if, bs_go;
    v2f whr;                           // (w_hr[0][j], w_hr[1][j]) unscaled
};

struct ChunkX {
    v2f   xif[CHUNK];                  // prescaled bias + x-part, gates (i,f)
    v2f   xgo[CHUNK];                  // prescaled bias + x-part, gates (g,o)
    float y0[CHUNK], y1[CHUNK];        // raw teacher h (est phase only)
};

__device__ __forceinline__ void load_chunk(float4* b, const float4* __restrict__ up, int base){
#pragma unroll
    for (int i = 0; i < CHUNK; ++i) b[i] = up[base + i];   // 16 independent dwordx4
}

template<bool TEACHER>
__device__ __forceinline__ void transform_chunk(ChunkX& X, const float4* raw, const LaneW& L){
#pragma unroll
    for (int i = 0; i < CHUNK; ++i) {
        const float4 x = raw[i];
        v2f xx = {x.x, x.x}, xy = {x.y, x.y};
        X.xif[i] = pk_fma(xy, L.wi1_if, pk_fma(xx, L.wi0_if, L.bs_if));
        X.xgo[i] = pk_fma(xy, L.wi1_go, pk_fma(xx, L.wi0_go, L.bs_go));
        if (TEACHER) { X.y0[i] = x.z; X.y1[i] = x.w; }
        else         { X.y0[i] = 0.f; X.y1[i] = 0.f; }
    }
}

template<bool TEACHER>
__device__ __forceinline__ void lstm_step(v2f xif, v2f xgo, float y0, float y1,
                                          const LaneW& L, float& c, v2f& rh)
{
    const float h0 = TEACHER ? y0 : rh.x;
    const float h1 = TEACHER ? y1 : rh.y;
    v2f hh0 = {h0, h0}, hh1 = {h1, h1};
    v2f gif = pk_fma(hh1, L.wh1_if, pk_fma(hh0, L.wh0_if, xif));  // (-L1C*i, -L1C*f)
    v2f ggo = pk_fma(hh1, L.wh1_go, pk_fma(hh0, L.wh0_go, xgo));  // ( L2C*g, -L1C*o)
    const float u  = fexp2(gif.x);     // e^-i   (|arg| < ~16, no clamp needed)
    const float ef = fexp2(gif.y);     // e^-f
    const float v  = fexp2(ggo.x);     // e^{2g}
    const float eo = fexp2(ggo.y);     // e^-o
    // c' = sigm(f)*c + sigm(i)*tanh(g) with ONE rcp:
    const float A   = (1.0f + u) * (v + 1.0f);
    const float B   = 1.0f + ef;
    const float t   = (v - 1.0f) * B;
    const float num = fmaf(c, A, t);
    c = num * frcp(A * B);
    const float w = fexp2(fminf(L2C * c, WCLAMP));                // e^{2c}
    const float s = (w - 1.0f) * frcp((1.0f + eo) * (w + 1.0f));  // sigm(o)*tanh(c)
    v2f ss = {s, s};
    rh = red16_2(ss * L.whr);          // packed projection + packed butterfly
}

// Branch-free chunk: per-step predicated capture (rh is broadcast to all 16
// lanes by the butterfly, so lane j keeps step base+j), ONE coalesced float2
// store per lane at the end. No divergent or uniform branches inside.
template<bool TEACHER>
__device__ __forceinline__ void chain_chunk(const ChunkX& X, int baseT, const LaneW& L,
                                            float& c, v2f& rh,
                                            float2* __restrict__ op2, int j)
{
    v2f cap = rh;
#pragma unroll
    for (int i = 0; i < CHUNK; ++i) {
        lstm_step<TEACHER>(X.xif[i], X.xgo[i], X.y0[i], X.y1[i], L, c, rh);
        cap = (j == i) ? rh : cap;     // v_cmp + 2x cndmask, no branch
    }
    float2 o; o.x = cap.x; o.y = cap.y;
    op2[baseT + j] = o;                // all 64 lanes store: 4 seqs x 16 t's
}

// 16 lanes per sequence (one per hidden unit); 4 sequences per wave; 1 wave/SIMD.
__global__ __launch_bounds__(256, 1) void openlstm_kernel(
    const float* __restrict__ u,     // (B, T, 4) = [x0 x1 y0 y1]
    const float* __restrict__ w_ih,  // (64, 2)
    const float* __restrict__ w_hh,  // (64, 2)
    const float* __restrict__ b_ih,  // (64)
    const float* __restrict__ b_hh,  // (64)
    const float* __restrict__ w_hr,  // (2, 16)
    float* __restrict__ out)         // (B, T, 2)
{
    const int tid = blockIdx.x * blockDim.x + threadIdx.x;
    const int seq = tid >> 4;
    const int j   = tid & 15;

    LaneW L;
    {   // gate rows {j, 16+j, 32+j, 48+j} = i, f, g, o ; prescale into exp2 domain
        const int ri = j, rf = 16 + j, rg = 32 + j, ro = 48 + j;
        const v2f sif = {-L1C, -L1C};
        const v2f sgo = { L2C, -L1C};
        L.wi0_if = sif * (v2f){w_ih[ri*2+0], w_ih[rf*2+0]};
        L.wi1_if = sif * (v2f){w_ih[ri*2+1], w_ih[rf*2+1]};
        L.wi0_go = sgo * (v2f){w_ih[rg*2+0], w_ih[ro*2+0]};
        L.wi1_go = sgo * (v2f){w_ih[rg*2+1], w_ih[ro*2+1]};
        L.wh0_if = sif * (v2f){w_hh[ri*2+0], w_hh[rf*2+0]};
        L.wh1_if = sif * (v2f){w_hh[ri*2+1], w_hh[rf*2+1]};
        L.wh0_go = sgo * (v2f){w_hh[rg*2+0], w_hh[ro*2+0]};
        L.wh1_go = sgo * (v2f){w_hh[rg*2+1], w_hh[ro*2+1]};
        L.bs_if  = sif * (v2f){b_ih[ri] + b_hh[ri], b_ih[rf] + b_hh[rf]};
        L.bs_go  = sgo * (v2f){b_ih[rg] + b_hh[rg], b_ih[ro] + b_hh[ro]};
        L.whr    = (v2f){w_hr[j], w_hr[16 + j]};
    }

    const float4* __restrict__ up = (const float4*)u + (size_t)seq * T_LEN;
    float2* __restrict__ op2 = (float2*)out + (size_t)seq * T_LEN;

    float c = 0.0f;
    v2f rh = {0.0f, 0.0f};
    float4 rawA[CHUNK], rawB[CHUNK];   // static ping-pong, never runtime-indexed

    load_chunk(rawA, up, 0);
    load_chunk(rawB, up, CHUNK);

    // ---- estimation: teacher-forced, chunks [0,16) ; loads stay in range ----
#pragma unroll 1
    for (int ck = 0; ck < CTXCK; ck += 2) {
        {
            ChunkX XA;
            transform_chunk<true>(XA, rawA, L);
            load_chunk(rawA, up, (ck + 2) * CHUNK);          // max chunk 16
            chain_chunk<true>(XA, ck * CHUNK, L, c, rh, op2, j);
        }
        {
            ChunkX XB;
            transform_chunk<true>(XB, rawB, L);
            load_chunk(rawB, up, (ck + 3) * CHUNK);          // max chunk 17
            chain_chunk<true>(XB, (ck + 1) * CHUNK, L, c, rh, op2, j);
        }
    }

    // ---- prediction: recurrent, chunks [16,32) ; clamped branch-free prefetch ----
#pragma unroll 1
    for (int ck = CTXCK; ck < NCHUNK; ck += 2) {
        const int lA = (ck + 2 < NCHUNK) ? (ck + 2) : (NCHUNK - 1);  // uniform SALU min
        const int lB = (ck + 3 < NCHUNK) ? (ck + 3) : (NCHUNK - 1);
        {
            ChunkX XA;
            transform_chunk<false>(XA, rawA, L);
            load_chunk(rawA, up, lA * CHUNK);
            chain_chunk<false>(XA, ck * CHUNK, L, c, rh, op2, j);
        }
        {
            ChunkX XB;
            transform_chunk<false>(XB, rawB, L);
            load_chunk(rawB, up, lB * CHUNK);
            chain_chunk<false>(XB, (ck + 1) * CHUNK, L, c, rh, op2, j);
        }
    }
}

extern "C" void kernel_launch(void* const* d_in, const int* in_sizes, int n_in,
                              void* d_out, int out_size, void* d_ws, size_t ws_size,
                              hipStream_t stream) {
    const float* u    = (const float*)d_in[0];
    const float* w_ih = (const float*)d_in[1];
    const float* w_hh = (const float*)d_in[2];
    const float* b_ih = (const float*)d_in[3];
    const float* b_hh = (const float*)d_in[4];
    const float* w_hr = (const float*)d_in[5];
    float* out = (float*)d_out;

    const int threads = 256;                       // 16 sequences / block
    const int blocks  = (N_SEQ * 16) / threads;    // 256 blocks -> 1 per CU
    hipLaunchKernelGGL(openlstm_kernel, dim3(blocks), dim3(threads), 0, stream,
                       u, w_ih, w_hh, b_ih, b_hh, w_hr, out);
}

// Round 7
// 214.068 us; speedup vs baseline: 1.8215x; 1.0169x over previous
//
#include <hip/hip_runtime.h>

#define N_CTX  256
#define T_LEN  1024
#define N_SEQ  4096
#define CHUNK  16
#define NCHUNK (T_LEN / CHUNK)          // 32
#define CTXCK  (N_CTX / CHUNK)          // 16 teacher-forced chunks

typedef float v2f __attribute__((ext_vector_type(2)));

__device__ __forceinline__ float fexp2(float x){ return __builtin_amdgcn_exp2f(x); }
__device__ __forceinline__ float frcp (float x){ return __builtin_amdgcn_rcpf(x); }
__device__ __forceinline__ v2f pk_fma(v2f a, v2f b, v2f c){ return __builtin_elementwise_fma(a, b, c); }

#define L1C 1.4426950408889634f   /* log2(e)   */
#define L2C 2.8853901631790583f   /* 2 log2(e) */
#define WCLAMP 100.0f             /* only the state-dependent exponent needs a clamp */

// ---- packed 16-lane butterfly via DPP ----
template<int CTRL>
__device__ __forceinline__ v2f dpp_add2(v2f x){
    int y0 = __builtin_amdgcn_mov_dpp(__float_as_int(x.x), CTRL, 0xf, 0xf, true);
    int y1 = __builtin_amdgcn_mov_dpp(__float_as_int(x.y), CTRL, 0xf, 0xf, true);
    v2f y = { __int_as_float(y0), __int_as_float(y1) };
    return x + y;
}
__device__ __forceinline__ v2f red16_2(v2f x){
    x = dpp_add2<0xB1>(x);    // quad_perm xor1
    x = dpp_add2<0x4E>(x);    // quad_perm xor2
    x = dpp_add2<0x124>(x);   // row_ror:4
    x = dpp_add2<0x128>(x);   // row_ror:8 -> full 16-lane sum, broadcast
    return x;
}

struct LaneW {                         // gate weights prescaled: (i,f,o)*-L1C, g*+L2C
    v2f wi0_if, wi1_if, wi0_go, wi1_go;
    v2f wh0_if, wh1_if, wh0_go, wh1_go;
    v2f bs_if, bs_go;
    v2f whr;                           // (w_hr[0][j], w_hr[1][j]) unscaled
};

__device__ __forceinline__ void load_chunk(float4* b, const float4* __restrict__ up, int base){
#pragma unroll
    for (int i = 0; i < CHUNK; ++i) b[i] = up[base + i];   // 16 independent dwordx4
}

// ================= ESTIMATION: batched, data-parallel per chunk =================
// Gates depend only on inputs (teacher h = y_t); only c is recurrent, and its
// recurrence is linear: c' = P*c + Q. Three passes: E1 parallel trans, E2 tiny
// fma-scan, E3 parallel tails. All arrays statically indexed (full unroll).
__device__ __forceinline__ void est_chunk(const float4* raw, int baseT, const LaneW& L,
                                          float& c, v2f& rh,
                                          float2* __restrict__ op2, int j)
{
    float P[CHUNK], Q[CHUNK], EO[CHUNK];
    // ---- E1: independent gate transcendentals for all 16 steps ----
#pragma unroll
    for (int i = 0; i < CHUNK; ++i) {
        const float4 x = raw[i];
        v2f xx = {x.x, x.x}, xy = {x.y, x.y};
        v2f y0 = {x.z, x.z}, y1 = {x.w, x.w};
        v2f gif = pk_fma(y1, L.wh1_if, pk_fma(y0, L.wh0_if,
                  pk_fma(xy, L.wi1_if, pk_fma(xx, L.wi0_if, L.bs_if))));
        v2f ggo = pk_fma(y1, L.wh1_go, pk_fma(y0, L.wh0_go,
                  pk_fma(xy, L.wi1_go, pk_fma(xx, L.wi0_go, L.bs_go))));
        const float u  = fexp2(gif.x);             // e^-i
        const float ef = fexp2(gif.y);             // e^-f
        const float v  = fexp2(ggo.x);             // e^{2g}
        const float eo = fexp2(ggo.y);             // e^-o
        const float A  = (1.0f + u) * (v + 1.0f);
        const float B  = 1.0f + ef;
        const float r  = frcp(A * B);
        P[i]  = A * r;                             // = sigmoid(f)
        Q[i]  = (v - 1.0f) * B * r;                // = sigm(i)*tanh(g)
        EO[i] = 1.0f + eo;
    }
    // ---- E2: the only recurrence — a 16-long fma chain ----
    float CA[CHUNK];
#pragma unroll
    for (int i = 0; i < CHUNK; ++i) { c = fmaf(P[i], c, Q[i]); CA[i] = c; }
    // ---- E3: independent output tails for all 16 steps ----
    v2f cap = rh;
#pragma unroll
    for (int i = 0; i < CHUNK; ++i) {
        const float w = fexp2(fminf(L2C * CA[i], WCLAMP));
        const float s = (w - 1.0f) * frcp(EO[i] * (w + 1.0f));
        v2f ss = {s, s};
        v2f hv = red16_2(ss * L.whr);
        cap = (j == i) ? hv : cap;
        if (i == CHUNK - 1) rh = hv;               // compile-time branch
    }
    float2 o; o.x = cap.x; o.y = cap.y;
    op2[baseT + j] = o;
}

// ================= PREDICTION: serial chain (h-recurrence irreducible) =========
struct ChunkX {
    v2f xif[CHUNK];                    // prescaled bias + x-part, gates (i,f)
    v2f xgo[CHUNK];                    // prescaled bias + x-part, gates (g,o)
};

__device__ __forceinline__ void transform_chunk(ChunkX& X, const float4* raw, const LaneW& L){
#pragma unroll
    for (int i = 0; i < CHUNK; ++i) {
        const float4 x = raw[i];
        v2f xx = {x.x, x.x}, xy = {x.y, x.y};
        X.xif[i] = pk_fma(xy, L.wi1_if, pk_fma(xx, L.wi0_if, L.bs_if));
        X.xgo[i] = pk_fma(xy, L.wi1_go, pk_fma(xx, L.wi0_go, L.bs_go));
    }
}

__device__ __forceinline__ void pred_step(v2f xif, v2f xgo, const LaneW& L,
                                          float& c, v2f& rh)
{
    v2f hh0 = {rh.x, rh.x}, hh1 = {rh.y, rh.y};
    v2f gif = pk_fma(hh1, L.wh1_if, pk_fma(hh0, L.wh0_if, xif));  // (-L1C*i, -L1C*f)
    v2f ggo = pk_fma(hh1, L.wh1_go, pk_fma(hh0, L.wh0_go, xgo));  // ( L2C*g, -L1C*o)
    const float u  = fexp2(gif.x);
    const float ef = fexp2(gif.y);
    const float v  = fexp2(ggo.x);
    const float eo = fexp2(ggo.y);
    const float A   = (1.0f + u) * (v + 1.0f);
    const float B   = 1.0f + ef;
    const float t   = (v - 1.0f) * B;
    const float num = fmaf(c, A, t);
    c = num * frcp(A * B);
    const float eop = 1.0f + eo;                                  // off-chain early
    const float w = fexp2(fminf(L2C * c, WCLAMP));
    const float s = (w - 1.0f) * frcp(eop * (w + 1.0f));
    v2f ss = {s, s};
    rh = red16_2(ss * L.whr);
}

__device__ __forceinline__ void pred_chunk(const ChunkX& X, int baseT, const LaneW& L,
                                           float& c, v2f& rh,
                                           float2* __restrict__ op2, int j)
{
    v2f cap = rh;
#pragma unroll
    for (int i = 0; i < CHUNK; ++i) {
        pred_step(X.xif[i], X.xgo[i], L, c, rh);
        cap = (j == i) ? rh : cap;     // predicated capture, no branch
    }
    float2 o; o.x = cap.x; o.y = cap.y;
    op2[baseT + j] = o;
}

// 16 lanes per sequence (one per hidden unit); 4 sequences per wave; 1 wave/SIMD.
__global__ __launch_bounds__(256, 1) void openlstm_kernel(
    const float* __restrict__ u,     // (B, T, 4) = [x0 x1 y0 y1]
    const float* __restrict__ w_ih,  // (64, 2)
    const float* __restrict__ w_hh,  // (64, 2)
    const float* __restrict__ b_ih,  // (64)
    const float* __restrict__ b_hh,  // (64)
    const float* __restrict__ w_hr,  // (2, 16)
    float* __restrict__ out)         // (B, T, 2)
{
    const int tid = blockIdx.x * blockDim.x + threadIdx.x;
    const int seq = tid >> 4;
    const int j   = tid & 15;

    LaneW L;
    {   // gate rows {j, 16+j, 32+j, 48+j} = i, f, g, o ; prescale into exp2 domain
        const int ri = j, rf = 16 + j, rg = 32 + j, ro = 48 + j;
        const v2f sif = {-L1C, -L1C};
        const v2f sgo = { L2C, -L1C};
        L.wi0_if = sif * (v2f){w_ih[ri*2+0], w_ih[rf*2+0]};
        L.wi1_if = sif * (v2f){w_ih[ri*2+1], w_ih[rf*2+1]};
        L.wi0_go = sgo * (v2f){w_ih[rg*2+0], w_ih[ro*2+0]};
        L.wi1_go = sgo * (v2f){w_ih[rg*2+1], w_ih[ro*2+1]};
        L.wh0_if = sif * (v2f){w_hh[ri*2+0], w_hh[rf*2+0]};
        L.wh1_if = sif * (v2f){w_hh[ri*2+1], w_hh[rf*2+1]};
        L.wh0_go = sgo * (v2f){w_hh[rg*2+0], w_hh[ro*2+0]};
        L.wh1_go = sgo * (v2f){w_hh[rg*2+1], w_hh[ro*2+1]};
        L.bs_if  = sif * (v2f){b_ih[ri] + b_hh[ri], b_ih[rf] + b_hh[rf]};
        L.bs_go  = sgo * (v2f){b_ih[rg] + b_hh[rg], b_ih[ro] + b_hh[ro]};
        L.whr    = (v2f){w_hr[j], w_hr[16 + j]};
    }

    const float4* __restrict__ up = (const float4*)u + (size_t)seq * T_LEN;
    float2* __restrict__ op2 = (float2*)out + (size_t)seq * T_LEN;

    float c = 0.0f;
    v2f rh = {0.0f, 0.0f};
    float4 rawA[CHUNK], rawB[CHUNK];   // static ping-pong, never runtime-indexed

    load_chunk(rawA, up, 0);
    load_chunk(rawB, up, CHUNK);

    // ---- estimation: batched data-parallel chunks [0,16) ----
#pragma unroll 1
    for (int ck = 0; ck < CTXCK; ck += 2) {
        est_chunk(rawA, ck * CHUNK, L, c, rh, op2, j);
        load_chunk(rawA, up, (ck + 2) * CHUNK);              // max chunk 16
        est_chunk(rawB, (ck + 1) * CHUNK, L, c, rh, op2, j);
        load_chunk(rawB, up, (ck + 3) * CHUNK);              // max chunk 17
    }

    // ---- prediction: recurrent chunks [16,32) ----
#pragma unroll 1
    for (int ck = CTXCK; ck < NCHUNK; ck += 2) {
        const int lA = (ck + 2 < NCHUNK) ? (ck + 2) : (NCHUNK - 1);
        const int lB = (ck + 3 < NCHUNK) ? (ck + 3) : (NCHUNK - 1);
        {
            ChunkX XA;
            transform_chunk(XA, rawA, L);
            load_chunk(rawA, up, lA * CHUNK);
            pred_chunk(XA, ck * CHUNK, L, c, rh, op2, j);
        }
        {
            ChunkX XB;
            transform_chunk(XB, rawB, L);
            load_chunk(rawB, up, lB * CHUNK);
            pred_chunk(XB, (ck + 1) * CHUNK, L, c, rh, op2, j);
        }
    }
}

extern "C" void kernel_launch(void* const* d_in, const int* in_sizes, int n_in,
                              void* d_out, int out_size, void* d_ws, size_t ws_size,
                              hipStream_t stream) {
    const float* u    = (const float*)d_in[0];
    const float* w_ih = (const float*)d_in[1];
    const float* w_hh = (const float*)d_in[2];
    const float* b_ih = (const float*)d_in[3];
    const float* b_hh = (const float*)d_in[4];
    const float* w_hr = (const float*)d_in[5];
    float* out = (float*)d_out;

    const int threads = 256;                       // 16 sequences / block
    const int blocks  = (N_SEQ * 16) / threads;    // 256 blocks -> 1 per CU
    hipLaunchKernelGGL(openlstm_kernel, dim3(blocks), dim3(threads), 0, stream,
                       u, w_ih, w_hh, b_ih, b_hh, w_hr, out);
}